// Round 10
// baseline (155.085 us; speedup 1.0000x reference)
//
#include <hip/hip_runtime.h>
#include <math.h>

#define Bsz 64
#define Tn 200
#define NUMC 2000
#define DS 128
#define SM 50
#define NTOK (Bsz*Tn)
#define NCH 4        // t-chunks (52/52/52/44)
#define CHL 52       // chunk length (last = 44)

typedef __attribute__((ext_vector_type(8))) short bfrag;
typedef __attribute__((ext_vector_type(4))) float f32x4;
typedef __attribute__((ext_vector_type(4))) unsigned int u32x4;

__device__ __forceinline__ unsigned short f2bf(float x) {
    unsigned int u = __builtin_bit_cast(unsigned int, x);
    u = u + 0x7fffu + ((u >> 16) & 1u);   // RNE
    return (unsigned short)(u >> 16);
}
__device__ __forceinline__ unsigned int pack2(float a, float b) {
    return (unsigned int)f2bf(a) | ((unsigned int)f2bf(b) << 16);
}
__device__ __forceinline__ bfrag mk_frag(f32x4 x, f32x4 y) {
    u32x4 t;
    t[0] = pack2(x[0], x[1]); t[1] = pack2(x[2], x[3]);
    t[2] = pack2(y[0], y[1]); t[3] = pack2(y[2], y[3]);
    return __builtin_bit_cast(bfrag, t);
}

// fast transcendentals: v_exp_f32 / v_rcp_f32 (~1e-6 rel err, invisible at bf16 grade)
__device__ __forceinline__ float fast_exp(float x)  { return __builtin_amdgcn_exp2f(x * 1.44269504f); }
__device__ __forceinline__ float fast_rcp(float x)  { return __builtin_amdgcn_rcpf(x); }
__device__ __forceinline__ float fast_sigmoid(float x) { return fast_rcp(1.f + fast_exp(-x)); }
__device__ __forceinline__ float fast_tanh(float x) { return 1.f - 2.f * fast_rcp(fast_exp(2.f * x) + 1.f); }

// ---------------- K0: cast weights into MFMA b-frag block layout ----------------
// lane L holds W[n = nt*16 + (L&15)][k = ki*32 + (L>>4)*8 + j], j=0..7.
// Bea: rows 0-127 = e_W, 128-255 = a_W          (16 n-tiles)
// Bkm: rows 0-127 = f_W[:,128:256], 128-177 = Mk, 178-191 = 0   (12 n-tiles)
// Bf0: rows 0-127 = f_W[:,0:128]                (8 n-tiles)
__global__ __launch_bounds__(256) void k0_cast(
    const float* __restrict__ eW, const float* __restrict__ aW,
    const float* __restrict__ fW, const float* __restrict__ Mk,
    unsigned int* __restrict__ BeaU, unsigned int* __restrict__ BkmU,
    unsigned int* __restrict__ Bf0U)
{
    const int g = blockIdx.x * 256 + threadIdx.x;
    if (g >= 9216) return;
    int gm, mat;
    unsigned int* dst;
    if (g < 4096)      { mat = 0; gm = g;        dst = BeaU; }
    else if (g < 7168) { mat = 1; gm = g - 4096; dst = BkmU; }
    else               { mat = 2; gm = g - 7168; dst = Bf0U; }
    const int nt = gm >> 8, r = gm & 255, ki = r >> 6, L = r & 63;
    const int n = nt * 16 + (L & 15);
    const int k = ki * 32 + (L >> 4) * 8;

    const float* src = nullptr;
    if (mat == 0) {
        src = (n < 128) ? (eW + (size_t)n * DS + k) : (aW + (size_t)(n - 128) * DS + k);
    } else if (mat == 1) {
        if (n < 128)      src = fW + (size_t)n * (2 * DS) + DS + k;
        else if (n < 128 + SM) src = Mk + (size_t)(n - 128) * DS + k;
    } else {
        src = fW + (size_t)n * (2 * DS) + k;
    }
    float v[8];
    #pragma unroll
    for (int j = 0; j < 8; j++) v[j] = src ? src[j] : 0.f;
    u32x4 o;
    o[0] = pack2(v[0], v[1]); o[1] = pack2(v[2], v[3]);
    o[2] = pack2(v[4], v[5]); o[3] = pack2(v[6], v[7]);
    ((u32x4*)dst)[gm] = o;
}

// ---------------- K1: 7 single-purpose waves per 16-token tile (5600 blocks) ----------------
// role 0/1: e cols 0-63/64-127 (V @ Bea[0:8],  sigmoid)
// role 2/3: a cols 0-63/64-127 (V @ Bea[8:16], tanh)
// role 4/5: kp cols 0-63/64-127 (K @ Bkm[0:8])
// role 6  : w logits (K @ Bkm[8:12]) + wave-parallel softmax -> w2[t][64] NATURAL order
//           (cols 0..49 = softmax w, cols 50..63 = 0)
__global__ __launch_bounds__(64, 4) void k1_gemm(
    const int* __restrict__ skill, const int* __restrict__ answer,
    const float* __restrict__ k_emb, const float* __restrict__ v_emb,
    const unsigned int* __restrict__ BeaU, const unsigned int* __restrict__ BkmU,
    const float* __restrict__ eB, const float* __restrict__ aB,
    float* __restrict__ w2, float* __restrict__ e_buf,
    float* __restrict__ a_buf, float* __restrict__ kp_buf)
{
    const int bid = blockIdx.x;
    const int tile = bid / 7, role = bid % 7;
    const int L = threadIdx.x, L15 = L & 15, quad = L >> 4;
    const int tok0 = tile * 16;
    const int tokA = tok0 + L15;
    const int row0 = tok0 + quad * 4;

    const int s = skill[tokA];
    const float* ap;
    if (role < 4) {
        const int an = answer[tokA];
        const int ax = (an == 2) ? 1 : an;
        ap = v_emb + ((size_t)(s + NUMC * ax)) * DS + quad * 8;
    } else {
        ap = k_emb + (size_t)s * DS + quad * 8;
    }
    bfrag Af[4];
    #pragma unroll
    for (int ki = 0; ki < 4; ki++) {
        const f32x4* a4 = (const f32x4*)(ap + ki * 32);
        Af[ki] = mk_frag(a4[0], a4[1]);
    }

    const bfrag* Bp = (role < 4) ? (const bfrag*)BeaU : (const bfrag*)BkmU;
    const int g0 = (role < 4) ? role * 4 : (role - 4) * 4;

    f32x4 acc[4];
    #pragma unroll
    for (int t = 0; t < 4; t++) acc[t] = (f32x4){0.f,0.f,0.f,0.f};

    // B in two 2-tile halves to keep VGPRs under the (64,4) cap
    #pragma unroll
    for (int half = 0; half < 2; half++) {
        bfrag bh[2][4];
        #pragma unroll
        for (int tt = 0; tt < 2; tt++)
            #pragma unroll
            for (int ki = 0; ki < 4; ki++)
                bh[tt][ki] = Bp[(size_t)((g0 + half * 2 + tt) * 4 + ki) * 64 + L];
        #pragma unroll
        for (int ki = 0; ki < 4; ki++)
            #pragma unroll
            for (int tt = 0; tt < 2; tt++)
                acc[half * 2 + tt] = __builtin_amdgcn_mfma_f32_16x16x32_bf16(
                    Af[ki], bh[tt][ki], acc[half * 2 + tt], 0, 0, 0);
    }

    if (role == 6) {
        #pragma unroll
        for (int reg = 0; reg < 4; reg++) {
            float mx = -1e30f;
            #pragma unroll
            for (int t = 0; t < 4; t++) { const int c = t * 16 + L15; if (c < SM) mx = fmaxf(mx, acc[t][reg]); }
            #pragma unroll
            for (int msk = 1; msk <= 8; msk <<= 1) mx = fmaxf(mx, __shfl_xor(mx, msk));
            float ex[4]; float ssum = 0.f;
            #pragma unroll
            for (int t = 0; t < 4; t++) {
                const int c = t * 16 + L15;
                ex[t] = (c < SM) ? fast_exp(acc[t][reg] - mx) : 0.f;
                ssum += ex[t];
            }
            #pragma unroll
            for (int msk = 1; msk <= 8; msk <<= 1) ssum += __shfl_xor(ssum, msk);
            const float inv = fast_rcp(ssum);
            float* wp = w2 + (size_t)(row0 + reg) * 64;
            // natural order: col c = m for c<50; c>=50 gets ex=0 (zero pad)
            #pragma unroll
            for (int t = 0; t < 4; t++) {
                const int c = t * 16 + L15;
                wp[c] = ex[t] * inv;
            }
        }
    } else {
        const int nb = (role & 1) * 64;
        float* obuf = (role < 2) ? e_buf : (role < 4) ? a_buf : kp_buf;
        const float* bias = (role < 2) ? eB : aB;
        #pragma unroll
        for (int t = 0; t < 4; t++) {
            const int n = nb + t * 16 + L15;
            const float bv = (role < 4) ? bias[n] : 0.f;
            #pragma unroll
            for (int reg = 0; reg < 4; reg++) {
                float v = acc[t][reg] + bv;
                if (role < 2)      v = fast_sigmoid(v);
                else if (role < 4) v = fast_tanh(v);
                obuf[(size_t)(row0 + reg) * DS + n] = v;
            }
        }
    }
}

// ================= two-pass t-parallel scan =================
// r4-r9 falsified: traffic, LDS latency, bank conflicts, barrier drains, raw TLP
// (0.5->2 waves/SIMD). k2 stuck ~40us, ~67% latency-stalled per wave. Remaining
// levers: waves/SIMD >= 4 (needs a bigger grid than b x d gives) AND shorter
// per-wave serial span. The affine recurrence Mv' = (1-w e) Mv + w a decomposes
// over t-chunks: k2a computes each chunk's propagator (P,Q) (Mv_end = P*Mv_start+Q
// per (m,d)); k2b folds the 3-step cross-chunk combine into its prologue and scans
// its own chunk with true start state -- identical per-t arithmetic to the serial
// version within each chunk, so only few-ulp start-state deviation before the
// existing bf16 rounding.
// Geometry (both): grid 64b x 16dseg x 4c = 4096 one-wave blocks (16 waves/CU,
// 4/SIMD, VGPR ~115). lane = (mg 0..7) x (dd 0..7): 8 m per lane (m = mg*8+j,
// cols >= 50 have w == 0 -> inert), 8 d per wave. w read as 2 aligned f32x4.

// ---------------- K2a: chunk propagators ----------------
__global__ __launch_bounds__(64) void k2a_prod(
    const float* __restrict__ w2, const float* __restrict__ e_buf,
    const float* __restrict__ a_buf,
    float* __restrict__ Pbuf, float* __restrict__ Qbuf)
{
    const int bid  = blockIdx.x;            // 0..4095
    const int b    = bid >> 6;
    const int r    = bid & 63;
    const int dseg = r >> 2;
    const int c    = r & 3;
    const int lane = threadIdx.x;
    const int mg   = lane >> 3;             // 0..7
    const int dd   = lane & 7;
    const int d    = dseg * 8 + dd;
    const int base = b * Tn;
    const int s    = c * CHL;
    const int npair = (c < 3) ? 6 : 5;      // PROC4 count = 2*npair+1 (13 / 11)

    float P[8], Q[8];
    #pragma unroll
    for (int j = 0; j < 8; j++) { P[j] = 1.f; Q[j] = 0.f; }

    float ev[2][4], av[2][4];
    f32x4 wva[2][4], wvb[2][4];

    #define LOADS(S, T0)                                                       \
        { _Pragma("unroll")                                                    \
          for (int i_ = 0; i_ < 4; i_++) {                                     \
              const int t_ = (T0) + i_;                                        \
              const int tc_ = (t_ < Tn) ? t_ : 0;                              \
              ev[S][i_] = e_buf[(size_t)(base + tc_) * DS + d];                \
              av[S][i_] = a_buf[(size_t)(base + tc_) * DS + d];                \
              const float* wp_ = w2 + (size_t)(base + tc_) * 64 + mg * 8;      \
              wva[S][i_] = *(const f32x4*)wp_;                                 \
              wvb[S][i_] = *(const f32x4*)(wp_ + 4);                           \
          } }

    #define PROC4A(S)                                                          \
        { _Pragma("unroll")                                                    \
          for (int it = 0; it < 4; it++) {                                     \
              const float ev_ = ev[S][it], av_ = av[S][it];                    \
              _Pragma("unroll")                                                \
              for (int j = 0; j < 8; j++) {                                    \
                  const float wm = (j < 4) ? wva[S][it][j] : wvb[S][it][j-4];  \
                  const float tmp = wm * ev_;                                  \
                  P[j] = fmaf(-tmp, P[j], P[j]);                               \
                  Q[j] = fmaf(-tmp, Q[j], Q[j]);                               \
                  Q[j] = fmaf(wm, av_, Q[j]);                                  \
              } } }

    LOADS(0, s) LOADS(1, s + 4)
    int t0 = s;
    for (int i = 0; i < npair; i++) {
        PROC4A(0) LOADS(0, t0 + 8)
        PROC4A(1) LOADS(1, t0 + 12)
        t0 += 8;
    }
    PROC4A(0)

    #pragma unroll
    for (int j = 0; j < 8; j++) {
        const size_t idx = (((size_t)c * Bsz + b) * 64 + mg * 8 + j) * DS + d;
        Pbuf[idx] = P[j];
        Qbuf[idx] = Q[j];
    }
    #undef LOADS
    #undef PROC4A
}

// ---------------- K2b: per-chunk scan with reconstructed start state ----------------
__global__ __launch_bounds__(64) void k2b_scan(
    const float* __restrict__ w2, const float* __restrict__ e_buf,
    const float* __restrict__ a_buf, const float* __restrict__ Mv0,
    const float* __restrict__ Pbuf, const float* __restrict__ Qbuf,
    unsigned short* __restrict__ reads)
{
    const int bid  = blockIdx.x;            // 0..4095
    const int b    = bid >> 6;
    const int r    = bid & 63;
    const int dseg = r >> 2;
    const int c    = r & 3;
    const int lane = threadIdx.x;
    const int mg   = lane >> 3;             // 0..7
    const int dd   = lane & 7;
    const int d    = dseg * 8 + dd;
    const int base = b * Tn;
    const int s    = c * CHL;
    const int npair = (c < 3) ? 6 : 5;

    // chunk-start state: Mv0 advanced through chunks < c via (P,Q)
    float Mv[8];
    #pragma unroll
    for (int j = 0; j < 8; j++) {
        const int m = mg * 8 + j;
        Mv[j] = Mv0[(size_t)((m < SM) ? m : (SM - 1)) * DS + d];  // pads: w==0 forever
    }
    for (int cc = 0; cc < c; cc++) {
        #pragma unroll
        for (int j = 0; j < 8; j++) {
            const size_t idx = (((size_t)cc * Bsz + b) * 64 + mg * 8 + j) * DS + d;
            Mv[j] = fmaf(Pbuf[idx], Mv[j], Qbuf[idx]);
        }
    }

    float ev[2][4], av[2][4];
    f32x4 wva[2][4], wvb[2][4];

    #define LOADS(S, T0)                                                       \
        { _Pragma("unroll")                                                    \
          for (int i_ = 0; i_ < 4; i_++) {                                     \
              const int t_ = (T0) + i_;                                        \
              const int tc_ = (t_ < Tn) ? t_ : 0;                              \
              ev[S][i_] = e_buf[(size_t)(base + tc_) * DS + d];                \
              av[S][i_] = a_buf[(size_t)(base + tc_) * DS + d];                \
              const float* wp_ = w2 + (size_t)(base + tc_) * 64 + mg * 8;      \
              wva[S][i_] = *(const f32x4*)wp_;                                 \
              wvb[S][i_] = *(const f32x4*)(wp_ + 4);                           \
          } }

    #define PROC4(S, T0)                                                       \
        { float r4[4];                                                         \
          _Pragma("unroll")                                                    \
          for (int it = 0; it < 4; it++) {                                     \
              const float ev_ = ev[S][it], av_ = av[S][it];                    \
              float rd = 0.f;                                                  \
              _Pragma("unroll")                                                \
              for (int j = 0; j < 8; j++) {                                    \
                  const float wm = (j < 4) ? wva[S][it][j] : wvb[S][it][j-4];  \
                  rd = fmaf(wm, Mv[j], rd);                        /* old Mv */\
                  Mv[j] = fmaf(-wm, fmaf(ev_, Mv[j], -av_), Mv[j]);            \
              }                                                                \
              rd += __shfl_xor(rd, 8);                                         \
              rd += __shfl_xor(rd, 16);                                        \
              rd += __shfl_xor(rd, 32);                                        \
              r4[it] = rd;                                                     \
          }                                                                    \
          if (mg < 4) {                                                        \
              const float val = (mg == 0) ? r4[0] : (mg == 1) ? r4[1]          \
                              : (mg == 2) ? r4[2] : r4[3];                     \
              reads[(size_t)(base + (T0) + mg) * DS + d] = f2bf(val);          \
          } }

    LOADS(0, s) LOADS(1, s + 4)
    int t0 = s;
    for (int i = 0; i < npair; i++) {
        PROC4(0, t0)     LOADS(0, t0 + 8)
        PROC4(1, t0 + 4) LOADS(1, t0 + 12)
        t0 += 8;
    }
    PROC4(0, t0)
    #undef LOADS
    #undef PROC4
}

// ---------------- K3: 2-wave blocks (n-halves); f-GEMM + pred with LDS combine ----------------
__global__ __launch_bounds__(128, 2) void k3_gemm(
    const unsigned short* __restrict__ reads, const float* __restrict__ kp_buf,
    const unsigned int* __restrict__ Bf0U, const float* __restrict__ fB,
    const float* __restrict__ pW, const float* __restrict__ pB,
    const int* __restrict__ skill, float* __restrict__ out)
{
    const int tid = threadIdx.x;
    const int wv  = tid >> 6;          // n-half: 0 -> cols 0-63, 1 -> cols 64-127
    const int L   = tid & 63, L15 = L & 15, quad = L >> 4;
    const int tok0 = blockIdx.x * 16;
    const int tokA = tok0 + L15;
    const int row0 = tok0 + quad * 4;

    __shared__ float sm[2][16];

    // A-frags: final reads, already bf16 in frag element order
    bfrag Rf[4];
    #pragma unroll
    for (int ki = 0; ki < 4; ki++)
        Rf[ki] = *(const bfrag*)(reads + (size_t)tokA * DS + ki * 32 + quad * 8);

    const bfrag* Bf0 = (const bfrag*)Bf0U;
    const int g0 = wv * 4;

    f32x4 acc[4];
    #pragma unroll
    for (int t = 0; t < 4; t++) acc[t] = (f32x4){0.f,0.f,0.f,0.f};

    #pragma unroll
    for (int half = 0; half < 2; half++) {
        bfrag bh[2][4];
        #pragma unroll
        for (int tt = 0; tt < 2; tt++)
            #pragma unroll
            for (int ki = 0; ki < 4; ki++)
                bh[tt][ki] = Bf0[(size_t)((g0 + half * 2 + tt) * 4 + ki) * 64 + L];
        #pragma unroll
        for (int ki = 0; ki < 4; ki++)
            #pragma unroll
            for (int tt = 0; tt < 2; tt++)
                acc[half * 2 + tt] = __builtin_amdgcn_mfma_f32_16x16x32_bf16(
                    Rf[ki], bh[tt][ki], acc[half * 2 + tt], 0, 0, 0);
    }

    const int nb = wv * 64;
    float f[4][4];   // [reg][t]
    #pragma unroll
    for (int t = 0; t < 4; t++) {
        const int n = nb + t * 16 + L15;
        const float fb = fB[n];
        #pragma unroll
        for (int reg = 0; reg < 4; reg++)
            f[reg][t] = fast_tanh(acc[t][reg] + kp_buf[(size_t)(row0 + reg) * DS + n] + fb);
    }

    // pred partial: this wave's 64-dim contribution, reduced over the 16 lanes (L15)
    #pragma unroll
    for (int reg = 0; reg < 4; reg++) {
        const int tok = row0 + reg;
        const int t = tok % Tn;
        const bool act = (t < Tn - 1);
        float contrib = 0.f;
        if (act) {
            const int sn = skill[tok + 1];
            const int ix = (sn < NUMC) ? sn : (NUMC - 1);
            const float* pr = pW + (size_t)ix * DS + nb + L15;
            #pragma unroll
            for (int t4 = 0; t4 < 4; t4++)
                contrib = fmaf(f[reg][t4], pr[t4 * 16], contrib);
        }
        #pragma unroll
        for (int msk = 1; msk <= 8; msk <<= 1)
            contrib += __shfl_xor(contrib, msk);
        if (L15 == 0) sm[wv][quad * 4 + reg] = contrib;
    }
    __syncthreads();
    if (tid < 16) {
        const int tok = tok0 + tid;
        const int t = tok % Tn;
        if (t < Tn - 1) {
            const int sn = skill[tok + 1];
            const int ix = (sn < NUMC) ? sn : (NUMC - 1);
            const float val = sm[0][tid] + sm[1][tid] + pB[ix];
            out[(size_t)(tok / Tn) * (Tn - 1) + t] = (sn < NUMC) ? fast_sigmoid(val) : 0.f;
        }
    }
}

extern "C" void kernel_launch(void* const* d_in, const int* in_sizes, int n_in,
                              void* d_out, int out_size, void* d_ws, size_t ws_size,
                              hipStream_t stream)
{
    const int*   skill  = (const int*)  d_in[0];
    const int*   answer = (const int*)  d_in[1];
    const float* k_emb  = (const float*)d_in[2];
    const float* v_emb  = (const float*)d_in[3];
    const float* Mk     = (const float*)d_in[4];
    const float* Mv0    = (const float*)d_in[5];
    const float* f_W    = (const float*)d_in[6];
    const float* f_b    = (const float*)d_in[7];
    const float* p_W    = (const float*)d_in[8];
    const float* p_b    = (const float*)d_in[9];
    const float* e_W    = (const float*)d_in[10];
    const float* e_b    = (const float*)d_in[11];
    const float* a_W    = (const float*)d_in[12];
    const float* a_b    = (const float*)d_in[13];
    float* out = (float*)d_out;

    float* ws     = (float*)d_ws;
    float* w2     = ws;                                   // NTOK*64 (natural-order w + zero pad)
    float* e_buf  = w2     + (size_t)NTOK*64;             // NTOK*DS
    float* a_buf  = e_buf  + (size_t)NTOK*DS;             // NTOK*DS
    float* kp_buf = a_buf  + (size_t)NTOK*DS;             // NTOK*DS
    unsigned short* reads = (unsigned short*)(kp_buf + (size_t)NTOK*DS);  // NTOK*DS bf16
    float* Pbuf   = (float*)(reads + (size_t)NTOK*DS);    // NCH*Bsz*64*DS
    float* Qbuf   = Pbuf   + (size_t)NCH*Bsz*64*DS;       // NCH*Bsz*64*DS
    unsigned int* BeaU = (unsigned int*)(Qbuf + (size_t)NCH*Bsz*64*DS);
    unsigned int* BkmU = BeaU + 4096 * 4;
    unsigned int* Bf0U = BkmU + 3072 * 4;

    k0_cast<<<36, 256, 0, stream>>>(e_W, a_W, f_W, Mk, BeaU, BkmU, Bf0U);
    k1_gemm<<<7*(NTOK/16), 64, 0, stream>>>(skill, answer, k_emb, v_emb,
        BeaU, BkmU, e_b, a_b, w2, e_buf, a_buf, kp_buf);
    k2a_prod<<<Bsz*64, 64, 0, stream>>>(w2, e_buf, a_buf, Pbuf, Qbuf);
    k2b_scan<<<Bsz*64, 64, 0, stream>>>(w2, e_buf, a_buf, Mv0, Pbuf, Qbuf, reads);
    k3_gemm<<<NTOK/16, 128, 0, stream>>>(reads, kp_buf, Bf0U, f_b,
        p_W, p_b, skill, out);
}

// Round 13
// 137.405 us; speedup vs baseline: 1.1287x; 1.1287x over previous
//
#include <hip/hip_runtime.h>
#include <math.h>

#define Bsz 64
#define Tn 200
#define NUMC 2000
#define DS 128
#define SM 50
#define NTOK (Bsz*Tn)

typedef __attribute__((ext_vector_type(8))) short bfrag;
typedef __attribute__((ext_vector_type(4))) float f32x4;
typedef __attribute__((ext_vector_type(4))) unsigned int u32x4;

__device__ __forceinline__ unsigned short f2bf(float x) {
    unsigned int u = __builtin_bit_cast(unsigned int, x);
    u = u + 0x7fffu + ((u >> 16) & 1u);   // RNE
    return (unsigned short)(u >> 16);
}
__device__ __forceinline__ unsigned int pack2(float a, float b) {
    return (unsigned int)f2bf(a) | ((unsigned int)f2bf(b) << 16);
}
__device__ __forceinline__ bfrag mk_frag(f32x4 x, f32x4 y) {
    u32x4 t;
    t[0] = pack2(x[0], x[1]); t[1] = pack2(x[2], x[3]);
    t[2] = pack2(y[0], y[1]); t[3] = pack2(y[2], y[3]);
    return __builtin_bit_cast(bfrag, t);
}

// fast transcendentals: v_exp_f32 / v_rcp_f32 (~1e-6 rel err, invisible at bf16 grade)
__device__ __forceinline__ float fast_exp(float x)  { return __builtin_amdgcn_exp2f(x * 1.44269504f); }
__device__ __forceinline__ float fast_rcp(float x)  { return __builtin_amdgcn_rcpf(x); }
__device__ __forceinline__ float fast_sigmoid(float x) { return fast_rcp(1.f + fast_exp(-x)); }
__device__ __forceinline__ float fast_tanh(float x) { return 1.f - 2.f * fast_rcp(fast_exp(2.f * x) + 1.f); }

// ---- inline-asm VMEM (counted-vmcnt ring; issue order/accounting controlled here) ----
__device__ __forceinline__ float gload_f32(const float* p) {
    float r;
    asm volatile("global_load_dword %0, %1, off" : "=v"(r) : "v"(p));
    return r;
}
__device__ __forceinline__ f32x4 gload_f32x4(const float* p) {
    f32x4 r;
    asm volatile("global_load_dwordx4 %0, %1, off" : "=v"(r) : "v"(p));
    return r;
}
__device__ __forceinline__ void gstore_u16(unsigned short* p, unsigned int v) {
    asm volatile("global_store_short %0, %1, off" :: "v"(p), "v"(v) : "memory");
}
#define WAITVM_(N) asm volatile("s_waitcnt vmcnt(" #N ")" ::: "memory")
#define WAITVM(N)  WAITVM_(N)

// ---------------- K0: cast weights into MFMA b-frag block layout ----------------
// lane L holds W[n = nt*16 + (L&15)][k = ki*32 + (L>>4)*8 + j], j=0..7.
// Bea: rows 0-127 = e_W, 128-255 = a_W          (16 n-tiles)
// Bkm: rows 0-127 = f_W[:,128:256], 128-177 = Mk, 178-191 = 0   (12 n-tiles)
// Bf0: rows 0-127 = f_W[:,0:128]                (8 n-tiles)
__global__ __launch_bounds__(256) void k0_cast(
    const float* __restrict__ eW, const float* __restrict__ aW,
    const float* __restrict__ fW, const float* __restrict__ Mk,
    unsigned int* __restrict__ BeaU, unsigned int* __restrict__ BkmU,
    unsigned int* __restrict__ Bf0U)
{
    const int g = blockIdx.x * 256 + threadIdx.x;
    if (g >= 9216) return;
    int gm, mat;
    unsigned int* dst;
    if (g < 4096)      { mat = 0; gm = g;        dst = BeaU; }
    else if (g < 7168) { mat = 1; gm = g - 4096; dst = BkmU; }
    else               { mat = 2; gm = g - 7168; dst = Bf0U; }
    const int nt = gm >> 8, r = gm & 255, ki = r >> 6, L = r & 63;
    const int n = nt * 16 + (L & 15);
    const int k = ki * 32 + (L >> 4) * 8;

    const float* src = nullptr;
    if (mat == 0) {
        src = (n < 128) ? (eW + (size_t)n * DS + k) : (aW + (size_t)(n - 128) * DS + k);
    } else if (mat == 1) {
        if (n < 128)      src = fW + (size_t)n * (2 * DS) + DS + k;
        else if (n < 128 + SM) src = Mk + (size_t)(n - 128) * DS + k;
    } else {
        src = fW + (size_t)n * (2 * DS) + k;
    }
    float v[8];
    #pragma unroll
    for (int j = 0; j < 8; j++) v[j] = src ? src[j] : 0.f;
    u32x4 o;
    o[0] = pack2(v[0], v[1]); o[1] = pack2(v[2], v[3]);
    o[2] = pack2(v[4], v[5]); o[3] = pack2(v[6], v[7]);
    ((u32x4*)dst)[gm] = o;
}

// ---------------- K1: 7 single-purpose waves per 16-token tile (5600 blocks) ----------------
// role 0/1: e cols 0-63/64-127 (V @ Bea[0:8],  sigmoid)
// role 2/3: a cols 0-63/64-127 (V @ Bea[8:16], tanh)
// role 4/5: kp cols 0-63/64-127 (K @ Bkm[0:8])
// role 6  : w logits (K @ Bkm[8:12]) + wave-parallel softmax -> w2[t][64] NATURAL order
//           (cols 0..49 = softmax w, cols 50..63 = 0)
__global__ __launch_bounds__(64, 4) void k1_gemm(
    const int* __restrict__ skill, const int* __restrict__ answer,
    const float* __restrict__ k_emb, const float* __restrict__ v_emb,
    const unsigned int* __restrict__ BeaU, const unsigned int* __restrict__ BkmU,
    const float* __restrict__ eB, const float* __restrict__ aB,
    float* __restrict__ w2, float* __restrict__ e_buf,
    float* __restrict__ a_buf, float* __restrict__ kp_buf)
{
    const int bid = blockIdx.x;
    const int tile = bid / 7, role = bid % 7;
    const int L = threadIdx.x, L15 = L & 15, quad = L >> 4;
    const int tok0 = tile * 16;
    const int tokA = tok0 + L15;
    const int row0 = tok0 + quad * 4;

    const int s = skill[tokA];
    const float* ap;
    if (role < 4) {
        const int an = answer[tokA];
        const int ax = (an == 2) ? 1 : an;
        ap = v_emb + ((size_t)(s + NUMC * ax)) * DS + quad * 8;
    } else {
        ap = k_emb + (size_t)s * DS + quad * 8;
    }
    bfrag Af[4];
    #pragma unroll
    for (int ki = 0; ki < 4; ki++) {
        const f32x4* a4 = (const f32x4*)(ap + ki * 32);
        Af[ki] = mk_frag(a4[0], a4[1]);
    }

    const bfrag* Bp = (role < 4) ? (const bfrag*)BeaU : (const bfrag*)BkmU;
    const int g0 = (role < 4) ? role * 4 : (role - 4) * 4;

    f32x4 acc[4];
    #pragma unroll
    for (int t = 0; t < 4; t++) acc[t] = (f32x4){0.f,0.f,0.f,0.f};

    // B in two 2-tile halves to keep VGPRs under the (64,4) cap
    #pragma unroll
    for (int half = 0; half < 2; half++) {
        bfrag bh[2][4];
        #pragma unroll
        for (int tt = 0; tt < 2; tt++)
            #pragma unroll
            for (int ki = 0; ki < 4; ki++)
                bh[tt][ki] = Bp[(size_t)((g0 + half * 2 + tt) * 4 + ki) * 64 + L];
        #pragma unroll
        for (int ki = 0; ki < 4; ki++)
            #pragma unroll
            for (int tt = 0; tt < 2; tt++)
                acc[half * 2 + tt] = __builtin_amdgcn_mfma_f32_16x16x32_bf16(
                    Af[ki], bh[tt][ki], acc[half * 2 + tt], 0, 0, 0);
    }

    if (role == 6) {
        #pragma unroll
        for (int reg = 0; reg < 4; reg++) {
            float mx = -1e30f;
            #pragma unroll
            for (int t = 0; t < 4; t++) { const int c = t * 16 + L15; if (c < SM) mx = fmaxf(mx, acc[t][reg]); }
            #pragma unroll
            for (int msk = 1; msk <= 8; msk <<= 1) mx = fmaxf(mx, __shfl_xor(mx, msk));
            float ex[4]; float ssum = 0.f;
            #pragma unroll
            for (int t = 0; t < 4; t++) {
                const int c = t * 16 + L15;
                ex[t] = (c < SM) ? fast_exp(acc[t][reg] - mx) : 0.f;
                ssum += ex[t];
            }
            #pragma unroll
            for (int msk = 1; msk <= 8; msk <<= 1) ssum += __shfl_xor(ssum, msk);
            const float inv = fast_rcp(ssum);
            float* wp = w2 + (size_t)(row0 + reg) * 64;
            // natural order: col c = m for c<50; c>=50 gets ex=0 (zero pad)
            #pragma unroll
            for (int t = 0; t < 4; t++) {
                const int c = t * 16 + L15;
                wp[c] = ex[t] * inv;
            }
        }
    } else {
        const int nb = (role & 1) * 64;
        float* obuf = (role < 2) ? e_buf : (role < 4) ? a_buf : kp_buf;
        const float* bias = (role < 2) ? eB : aB;
        #pragma unroll
        for (int t = 0; t < 4; t++) {
            const int n = nb + t * 16 + L15;
            const float bv = (role < 4) ? bias[n] : 0.f;
            #pragma unroll
            for (int reg = 0; reg < 4; reg++) {
                float v = acc[t][reg] + bv;
                if (role < 2)      v = fast_sigmoid(v);
                else if (role < 4) v = fast_tanh(v);
                obuf[(size_t)(row0 + reg) * DS + n] = v;
            }
        }
    }
}

// ---------------- K2: barrier-free scan, asm counted-vmcnt ring (T4) ----------------
// r11 failure post-mortem: tail undercount -- vmcnt(36) is weaker than needed once
// outstanding < 37 (last 3 groups have slack 27/15/3, not 39). Exact ledger (prologue
// 48 loads; full group = 1 store + 12 loads; 44 full groups in-loop + 2 full + 4
// store-only tail groups):
//   k=0: slack 36 ... steady k: 39 -> vmcnt(36) safe through k=46
//   k=47 (t0=188): 27   k=48 (t0=192): 15   k=49 (t0=196): 3
// Also drain vmcnt(0) after Mv0 init so the compiler's own loads can't pollute the
// ledger. Geometry/arithmetic identical to r9 (2048 one-wave blocks, lane = mg x dd,
// 4 m/lane, shfl_xor m-reduce, lanes mg<4 store).
__global__ __launch_bounds__(64) void k2_scan(
    const float* __restrict__ w2, const float* __restrict__ e_buf,
    const float* __restrict__ a_buf, const float* __restrict__ Mv0,
    unsigned short* __restrict__ reads)
{
    const int bid  = blockIdx.x;            // 0..2047
    const int b    = bid >> 5;
    const int dseg = bid & 31;
    const int lane = threadIdx.x;
    const int mg   = lane >> 2;             // 0..15 m-group
    const int dd   = lane & 3;
    const int d    = dseg * 4 + dd;
    const int m0   = mg * 4;
    const int base = b * Tn;

    float Mv[4];
    #pragma unroll
    for (int j = 0; j < 4; j++) {
        const int m = (m0 + j < SM) ? (m0 + j) : (SM - 1);  // pad slots: finite value, w=0 forever
        Mv[j] = Mv0[(size_t)m * DS + d];
    }
    // ledger hygiene: compiler's Mv0 loads fully retired before the asm ring starts
    WAITVM(0);
    __builtin_amdgcn_sched_barrier(0);

    // 4-slot x 4-t asm ring
    float ev[4][4], av[4][4];
    f32x4 wv[4][4];

    #define LOADS(S, T0)                                                       \
        { _Pragma("unroll")                                                    \
          for (int i_ = 0; i_ < 4; i_++) {                                     \
              const int t_ = (T0) + i_;                                        \
              ev[S][i_] = gload_f32(e_buf + (size_t)(base + t_) * DS + d);     \
              av[S][i_] = gload_f32(a_buf + (size_t)(base + t_) * DS + d);     \
              wv[S][i_] = gload_f32x4(w2 + (size_t)(base + t_) * 64 + m0);     \
          } }

    #define PROC4(S, T0)                                                       \
        { float r4[4];                                                         \
          _Pragma("unroll")                                                    \
          for (int it = 0; it < 4; it++) {                                     \
              const float ev_ = ev[S][it], av_ = av[S][it];                    \
              float rd = 0.f;                                                  \
              _Pragma("unroll")                                                \
              for (int j = 0; j < 4; j++) {                                    \
                  const float wm = wv[S][it][j];                               \
                  rd = fmaf(wm, Mv[j], rd);                        /* old Mv */\
                  Mv[j] = fmaf(-wm, fmaf(ev_, Mv[j], -av_), Mv[j]);            \
              }                                                                \
              rd += __shfl_xor(rd, 4);                                         \
              rd += __shfl_xor(rd, 8);                                         \
              rd += __shfl_xor(rd, 16);                                        \
              rd += __shfl_xor(rd, 32);                                        \
              r4[it] = rd;                                                     \
          }                                                                    \
          if (mg < 4) {                                                        \
              const float val = (mg == 0) ? r4[0] : (mg == 1) ? r4[1]          \
                              : (mg == 2) ? r4[2] : r4[3];                     \
              gstore_u16(reads + (size_t)(base + (T0) + mg) * DS + d,          \
                         (unsigned int)f2bf(val));                             \
          } }

    // group with prefetch of T0+16 (valid: T0+16 <= 196 always where used)
    #define GROUPL(S, T0, N)                                                   \
        { WAITVM(N);                                                           \
          __builtin_amdgcn_sched_barrier(0);                                   \
          PROC4(S, T0)                                                         \
          __builtin_amdgcn_sched_barrier(0);                                   \
          LOADS(S, (T0) + 16)                                                  \
          __builtin_amdgcn_sched_barrier(0); }
    // store-only group (no prefetch), exact counted wait
    #define GROUPN(S, T0, N)                                                   \
        { WAITVM(N);                                                           \
          __builtin_amdgcn_sched_barrier(0);                                   \
          PROC4(S, T0)                                                         \
          __builtin_amdgcn_sched_barrier(0); }

    LOADS(0, 0) LOADS(1, 4) LOADS(2, 8) LOADS(3, 12)

    // 44 full groups: t0 = 0..172 (prefetch up to t=188..191)
    for (int gg = 0; gg < 11; gg++) {
        const int gb = gg * 16;
        GROUPL(0, gb,      36)
        GROUPL(1, gb + 4,  36)
        GROUPL(2, gb + 8,  36)
        GROUPL(3, gb + 12, 36)
    }
    // tail: two full groups (prefetch 192, 196), then store-only with exact waits
    GROUPL(0, 176, 36)      // prefetches t=192..195
    GROUPL(1, 180, 36)      // prefetches t=196..199
    GROUPN(2, 184, 36)      // slack 39
    GROUPN(3, 188, 27)
    GROUPN(0, 192, 15)
    GROUPN(1, 196, 3)
    #undef LOADS
    #undef PROC4
    #undef GROUPL
    #undef GROUPN
}

// ---------------- K3: 2-wave blocks (n-halves); f-GEMM + pred with LDS combine ----------------
__global__ __launch_bounds__(128, 2) void k3_gemm(
    const unsigned short* __restrict__ reads, const float* __restrict__ kp_buf,
    const unsigned int* __restrict__ Bf0U, const float* __restrict__ fB,
    const float* __restrict__ pW, const float* __restrict__ pB,
    const int* __restrict__ skill, float* __restrict__ out)
{
    const int tid = threadIdx.x;
    const int wv  = tid >> 6;          // n-half: 0 -> cols 0-63, 1 -> cols 64-127
    const int L   = tid & 63, L15 = L & 15, quad = L >> 4;
    const int tok0 = blockIdx.x * 16;
    const int tokA = tok0 + L15;
    const int row0 = tok0 + quad * 4;

    __shared__ float sm[2][16];

    // A-frags: final reads, already bf16 in frag element order
    bfrag Rf[4];
    #pragma unroll
    for (int ki = 0; ki < 4; ki++)
        Rf[ki] = *(const bfrag*)(reads + (size_t)tokA * DS + ki * 32 + quad * 8);

    const bfrag* Bf0 = (const bfrag*)Bf0U;
    const int g0 = wv * 4;

    f32x4 acc[4];
    #pragma unroll
    for (int t = 0; t < 4; t++) acc[t] = (f32x4){0.f,0.f,0.f,0.f};

    #pragma unroll
    for (int half = 0; half < 2; half++) {
        bfrag bh[2][4];
        #pragma unroll
        for (int tt = 0; tt < 2; tt++)
            #pragma unroll
            for (int ki = 0; ki < 4; ki++)
                bh[tt][ki] = Bf0[(size_t)((g0 + half * 2 + tt) * 4 + ki) * 64 + L];
        #pragma unroll
        for (int ki = 0; ki < 4; ki++)
            #pragma unroll
            for (int tt = 0; tt < 2; tt++)
                acc[half * 2 + tt] = __builtin_amdgcn_mfma_f32_16x16x32_bf16(
                    Rf[ki], bh[tt][ki], acc[half * 2 + tt], 0, 0, 0);
    }

    const int nb = wv * 64;
    float f[4][4];   // [reg][t]
    #pragma unroll
    for (int t = 0; t < 4; t++) {
        const int n = nb + t * 16 + L15;
        const float fb = fB[n];
        #pragma unroll
        for (int reg = 0; reg < 4; reg++)
            f[reg][t] = fast_tanh(acc[t][reg] + kp_buf[(size_t)(row0 + reg) * DS + n] + fb);
    }

    // pred partial: this wave's 64-dim contribution, reduced over the 16 lanes (L15)
    #pragma unroll
    for (int reg = 0; reg < 4; reg++) {
        const int tok = row0 + reg;
        const int t = tok % Tn;
        const bool act = (t < Tn - 1);
        float contrib = 0.f;
        if (act) {
            const int sn = skill[tok + 1];
            const int ix = (sn < NUMC) ? sn : (NUMC - 1);
            const float* pr = pW + (size_t)ix * DS + nb + L15;
            #pragma unroll
            for (int t4 = 0; t4 < 4; t4++)
                contrib = fmaf(f[reg][t4], pr[t4 * 16], contrib);
        }
        #pragma unroll
        for (int msk = 1; msk <= 8; msk <<= 1)
            contrib += __shfl_xor(contrib, msk);
        if (L15 == 0) sm[wv][quad * 4 + reg] = contrib;
    }
    __syncthreads();
    if (tid < 16) {
        const int tok = tok0 + tid;
        const int t = tok % Tn;
        if (t < Tn - 1) {
            const int sn = skill[tok + 1];
            const int ix = (sn < NUMC) ? sn : (NUMC - 1);
            const float val = sm[0][tid] + sm[1][tid] + pB[ix];
            out[(size_t)(tok / Tn) * (Tn - 1) + t] = (sn < NUMC) ? fast_sigmoid(val) : 0.f;
        }
    }
}

extern "C" void kernel_launch(void* const* d_in, const int* in_sizes, int n_in,
                              void* d_out, int out_size, void* d_ws, size_t ws_size,
                              hipStream_t stream)
{
    const int*   skill  = (const int*)  d_in[0];
    const int*   answer = (const int*)  d_in[1];
    const float* k_emb  = (const float*)d_in[2];
    const float* v_emb  = (const float*)d_in[3];
    const float* Mk     = (const float*)d_in[4];
    const float* Mv0    = (const float*)d_in[5];
    const float* f_W    = (const float*)d_in[6];
    const float* f_b    = (const float*)d_in[7];
    const float* p_W    = (const float*)d_in[8];
    const float* p_b    = (const float*)d_in[9];
    const float* e_W    = (const float*)d_in[10];
    const float* e_b    = (const float*)d_in[11];
    const float* a_W    = (const float*)d_in[12];
    const float* a_b    = (const float*)d_in[13];
    float* out = (float*)d_out;

    float* ws     = (float*)d_ws;
    float* w2     = ws;                                   // NTOK*64 (natural-order w + zero pad)
    float* e_buf  = w2     + (size_t)NTOK*64;             // NTOK*DS
    float* a_buf  = e_buf  + (size_t)NTOK*DS;             // NTOK*DS
    float* kp_buf = a_buf  + (size_t)NTOK*DS;             // NTOK*DS
    unsigned short* reads = (unsigned short*)(kp_buf + (size_t)NTOK*DS);  // NTOK*DS bf16
    unsigned int* BeaU = (unsigned int*)(reads + (size_t)NTOK*DS);
    unsigned int* BkmU = BeaU + 4096 * 4;
    unsigned int* Bf0U = BkmU + 3072 * 4;

    k0_cast<<<36, 256, 0, stream>>>(e_W, a_W, f_W, Mk, BeaU, BkmU, Bf0U);
    k1_gemm<<<7*(NTOK/16), 64, 0, stream>>>(skill, answer, k_emb, v_emb,
        BeaU, BkmU, e_b, a_b, w2, e_buf, a_buf, kp_buf);
    k2_scan<<<Bsz*32, 64, 0, stream>>>(w2, e_buf, a_buf, Mv0, reads);
    k3_gemm<<<NTOK/16, 128, 0, stream>>>(reads, kp_buf, Bf0U, f_b,
        p_W, p_b, skill, out);
}